// Round 13
// baseline (171.816 us; speedup 1.0000x reference)
//
#include <hip/hip_runtime.h>
#include <math.h>

#define HH 512
#define WW 512
#define NPIX (HH*WW)
#define NB 32
#define NS 21           // 2*MS+1 shifts per axis
#define KWIN 492        // window size (H - 2*10)
#define NKB 256         // split-K chunks (1024 k each)
#define MT28 28         // m-tiles (448 = 28*16, M=441 padded)
#define PARTSZ (MT28*32*16)   // 14336 floats per k-chunk
#define TPLB_COPY 278528      // 512*544 shorts per parity copy

typedef __attribute__((ext_vector_type(8))) short short8;
typedef __attribute__((ext_vector_type(4))) float floatx4;

__device__ __forceinline__ unsigned short f2bf(float f) {
    unsigned u = __float_as_uint(f);
    unsigned r = (u + 0x7fffu + ((u >> 16) & 1u)) >> 16;
    return (unsigned short)r;
}

// 16B fragment load from a 4B-aligned address (tplb cols are even, not x8).
__device__ __forceinline__ short8 loadA(const unsigned short* p) {
    union { short8 v; unsigned u[4]; } r;
    const unsigned* q = (const unsigned*)p;
    r.u[0] = q[0]; r.u[1] = q[1]; r.u[2] = q[2]; r.u[3] = q[3];
    return r.v;
}

// ---------------- prep: interior col partial sums (256 blk), template partial
//   sums (64 blk), padded bf16 template (128 blk). No atomics, no flag.
__global__ __launch_bounds__(512) void prep(
    const float* __restrict__ fr, const float* __restrict__ tpl,
    unsigned short* __restrict__ tplb,
    float* __restrict__ I1p, float* __restrict__ I2p,
    double* __restrict__ tplS1p, double* __restrict__ tplS2p)
{
    int blk = blockIdx.x;
    int t   = threadIdx.x;

    if (blk < 256) {
        // interior column partial sums: (frame b, row-oct) -> I1p/I2p
        int b = blk >> 3, oct = blk & 7;              // b in [0,32)
        const float* img = fr + (size_t)b * NPIX;
        int x = t;
        float s1 = 0.f, s2 = 0.f;
        int y0 = 20 + 59 * oct;                       // rows 20..491 = 8*59
        for (int y = y0; y < y0 + 59; ++y) {
            float v = img[(size_t)y * WW + x];
            s1 += v; s2 += v * v;
        }
        I1p[(size_t)blk * 512 + x] = s1;
        I2p[(size_t)blk * 512 + x] = s2;
    } else if (blk < 320) {
        // template partial sums: 64 jobs of 8 rows
        __shared__ double jb1[8], jb2[8];
        int tj = blk - 256;
        const float* trow = tpl + (size_t)tj * 8 * WW;
        float s1 = 0.f, s2 = 0.f;
        int x = t;
        for (int y = 0; y < 8; ++y) {
            float v = trow[(size_t)y * WW + x];
            s1 += v; s2 += v * v;
        }
        double d1 = (double)s1, d2 = (double)s2;
        for (int off = 32; off; off >>= 1) {
            d1 += __shfl_down(d1, off);
            d2 += __shfl_down(d2, off);
        }
        int lane = t & 63, wv = t >> 6;
        if (lane == 0) { jb1[wv] = d1; jb2[wv] = d2; }
        __syncthreads();
        if (t == 0) {
            double a = 0.0, c = 0.0;
            for (int i = 0; i < 8; ++i) { a += jb1[i]; c += jb2[i]; }
            tplS1p[tj] = a; tplS2p[tj] = c;
        }
    } else {
        // padded bf16 template: copyP[sy][c] = bf16(tpl[sy][(c-16-P) mod 512])
        int sy0 = (blk - 320) * 4;                    // 128 blocks x 4 rows
#pragma unroll
        for (int rr = 0; rr < 4; ++rr) {
            int sy = sy0 + rr;
            const float* srow = tpl + (size_t)sy * WW;
#pragma unroll
            for (int P = 0; P < 2; ++P) {
                for (int c = t; c < 544; c += 512) {
                    int sx = (c + 496 - P) & 511;     // (c-16-P) mod 512
                    tplb[(size_t)P * TPLB_COPY + (size_t)sy * 544 + c] = f2bf(srow[sx]);
                }
            }
        }
    }
}

// ---------------- Kernel C: implicit-GEMM correlation via MFMA --------------
// NKB=256 chunks of 1024 k. 896 thr = 14 waves x 2 m-tiles, 1 block/CU.
// T14 async-STAGE, spill-fixed (R12 post-mortem: VGPR_Count=64 + 107MB
// WRITE_SIZE = scratch spills from 40 staged VGPRs under the compiler's
// 64-reg heuristic): __launch_bounds__(896,4) raises the cap to 128, and
// only buf1 is register-staged (20 VGPRs live across MFMA0). buf0 goes
// straight to LDS; buf1's loads are issued before the first barrier so the
// HBM latency hides under MFMA(buf0).
__global__ __launch_bounds__(896, 4) void corr_mfma(
    const float* __restrict__ fr,
    const unsigned short* __restrict__ tplb,
    float* __restrict__ part)
{
    __shared__ unsigned short Bs[2][16384];   // 2 x 32 KB = 64 KB

    const int t   = threadIdx.x;
    const int l   = t & 63;
    const int wid = t >> 6;               // wave 0..13 = tile-pair
    const int idx = blockIdx.x;           // 0..255
    const int kb  = ((idx & 7) << 5) | (idx >> 3);   // XCD swizzle (32/XCD)
    const int kg  = l >> 4;               // k-group 0..3
    const int ln  = l & 15;

    // m-geometry (sub-chunk independent)
    int du0, dv0, du1, dv1;
    {
        int m_g = 32 * wid + ln;           // mt = 0
        du0 = (m_g * 1561) >> 15;          // m_g/21 exact for m_g<=447
        dv0 = m_g - 21 * du0;
        if (m_g >= 441) { du0 = 0; dv0 = 0; }   // pad rows: loaded, never used
        m_g = 32 * wid + 16 + ln;          // mt = 1
        du1 = (m_g * 1561) >> 15;
        dv1 = m_g - 21 * du1;
        if (m_g >= 441) { du1 = 0; dv1 = 0; }
    }
    const int P0 = dv0 & 1, P1 = dv1 & 1;
    const int col0 = 8 * kg - dv0 + 26 + P0;
    const int col1 = 8 * kg - dv1 + 26 + P1;

    const unsigned short* lB0 = Bs[0] + kg * 256 + ln * 8;
    const unsigned short* lB1 = Bs[1] + kg * 256 + ln * 8;

    const int k0a = (2 * kb)     << 9;
    const int k0b = (2 * kb + 1) << 9;

    // buf0: load -> LDS immediately (no long-lived registers)
#pragma unroll
    for (int s = 0; s < 5; ++s) {
        int i = t + 896 * s;
        if (i < 4096) {
            int frame = i >> 7, q = i & 127;
            float4 v = *(const float4*)(fr + (size_t)frame * NPIX + k0a + 4 * q);
            int k8 = q >> 1, j4 = (q & 1) * 4;
            ushort4 o;
            o.x = f2bf(v.x); o.y = f2bf(v.y); o.z = f2bf(v.z); o.w = f2bf(v.w);
            *(ushort4*)&Bs[0][(k8 * 32 + frame) * 8 + j4] = o;
        }
    }
    // buf1: ISSUE loads now (20 VGPRs); they land while MFMA(buf0) runs
    float4 w[5];
#pragma unroll
    for (int s = 0; s < 5; ++s) {
        int i = t + 896 * s;
        if (i < 4096) {
            int frame = i >> 7, q = i & 127;
            w[s] = *(const float4*)(fr + (size_t)frame * NPIX + k0b + 4 * q);
        }
    }
    __syncthreads();

    floatx4 acc00 = {}, acc01 = {}, acc10 = {}, acc11 = {};

    // ---- MFMA over buf0 (row 2*kb) while buf1's loads are in flight -------
    {
        const int row = 2 * kb;
        const unsigned short* pA0 = tplb + (size_t)P0 * TPLB_COPY
            + (size_t)((row + 522 - du0) & 511) * 544 + col0;
        const unsigned short* pA1 = tplb + (size_t)P1 * TPLB_COPY
            + (size_t)((row + 522 - du1) & 511) * 544 + col1;
#pragma unroll
        for (int ks = 0; ks < 16; ++ks) {
            short8 A0 = loadA(pA0);
            short8 A1 = loadA(pA1);
            short8 B0 = *(const short8*)(lB0 + ks * 1024);
            short8 B1 = *(const short8*)(lB0 + ks * 1024 + 128);
            acc00 = __builtin_amdgcn_mfma_f32_16x16x32_bf16(A0, B0, acc00, 0, 0, 0);
            acc01 = __builtin_amdgcn_mfma_f32_16x16x32_bf16(A0, B1, acc01, 0, 0, 0);
            acc10 = __builtin_amdgcn_mfma_f32_16x16x32_bf16(A1, B0, acc10, 0, 0, 0);
            acc11 = __builtin_amdgcn_mfma_f32_16x16x32_bf16(A1, B1, acc11, 0, 0, 0);
            pA0 += 32; pA1 += 32;
        }
    }

    // write buf1 (loads long since landed; different buffer, no WAR on buf0)
#pragma unroll
    for (int s = 0; s < 5; ++s) {
        int i = t + 896 * s;
        if (i < 4096) {
            int frame = i >> 7, q = i & 127;
            int k8 = q >> 1, j4 = (q & 1) * 4;
            ushort4 o;
            o.x = f2bf(w[s].x); o.y = f2bf(w[s].y);
            o.z = f2bf(w[s].z); o.w = f2bf(w[s].w);
            *(ushort4*)&Bs[1][(k8 * 32 + frame) * 8 + j4] = o;
        }
    }
    __syncthreads();

    // ---- MFMA over buf1 (row 2*kb+1), accumulating ------------------------
    {
        const int row = 2 * kb + 1;
        const unsigned short* pA0 = tplb + (size_t)P0 * TPLB_COPY
            + (size_t)((row + 522 - du0) & 511) * 544 + col0;
        const unsigned short* pA1 = tplb + (size_t)P1 * TPLB_COPY
            + (size_t)((row + 522 - du1) & 511) * 544 + col1;
#pragma unroll
        for (int ks = 0; ks < 16; ++ks) {
            short8 A0 = loadA(pA0);
            short8 A1 = loadA(pA1);
            short8 B0 = *(const short8*)(lB1 + ks * 1024);
            short8 B1 = *(const short8*)(lB1 + ks * 1024 + 128);
            acc00 = __builtin_amdgcn_mfma_f32_16x16x32_bf16(A0, B0, acc00, 0, 0, 0);
            acc01 = __builtin_amdgcn_mfma_f32_16x16x32_bf16(A0, B1, acc01, 0, 0, 0);
            acc10 = __builtin_amdgcn_mfma_f32_16x16x32_bf16(A1, B0, acc10, 0, 0, 0);
            acc11 = __builtin_amdgcn_mfma_f32_16x16x32_bf16(A1, B1, acc11, 0, 0, 0);
            pA0 += 32; pA1 += 32;
        }
    }

    // dense partial stores: part[((kb*28 + mtile)*32 + n)*16 + mr], mr=4kg+r
    {
        size_t base = ((size_t)kb * MT28 + 2 * wid) * 32;
        floatx4* p;
        p = (floatx4*)(part + (base + ln)      * 16 + 4 * kg); *p = acc00;
        p = (floatx4*)(part + (base + 16 + ln) * 16 + 4 * kg); *p = acc01;
        p = (floatx4*)(part + (base + 32 + ln) * 16 + 4 * kg); *p = acc10;
        p = (floatx4*)(part + (base + 48 + ln) * 16 + 4 * kg); *p = acc11;
    }
}

// ---------------- reduce: part (256 k-chunks) -> cc8 (8 oct partials) -------
// 224 blocks x 512. Disjoint writes, no atomics. Kernel boundary provides
// cross-XCD visibility to stage2_am (no flag/spin).
__global__ __launch_bounds__(512) void reduce_k(
    const float* __restrict__ part, float* __restrict__ cc8)
{
    int blk = blockIdx.x;
    int oct = blk / 28;                      // 0..7 (32 kb-chunks each)
    int j   = (blk % 28) * 512 + threadIdx.x;
    const float* p = part + (size_t)(oct * 32) * PARTSZ + j;
    float s = 0.f;
#pragma unroll 8
    for (int i = 0; i < 32; ++i)
        s += p[(size_t)i * PARTSZ];
    cc8[(size_t)oct * PARTSZ + j] = s;
}

// ---------------- stage2 + argmax + subpixel: 32 blocks (one per frame) -----
__global__ __launch_bounds__(512) void stage2_am(
    const float* __restrict__ cc8, const float* __restrict__ fr,
    const float* __restrict__ I1p, const float* __restrict__ I2p,
    const double* __restrict__ tplS1p, const double* __restrict__ tplS2p,
    float* __restrict__ shifts)
{
    __shared__ double wr1[NS][8], wr2[NS][8], wrT[8];
    __shared__ float  e1[NS][40], e2[NS][40];
    __shared__ double totals1[NS], totals2[NS];
    __shared__ float  denomS[NS * NS];
    __shared__ double tS1s, tS2s, sum1b;

    int b = blockIdx.x;
    int x = threadIdx.x;
    const float* img = fr + (size_t)b * NPIX;
    float top[20], bot[20];
#pragma unroll
    for (int y = 0; y < 20; ++y) top[y] = img[(size_t)y * WW + x];
#pragma unroll
    for (int y = 0; y < 20; ++y) bot[y] = img[(size_t)(492 + y) * WW + x];

    float t1 = 0.f, t2 = 0.f, b1 = 0.f, b2 = 0.f;
#pragma unroll
    for (int y = 0; y < 20; ++y) {
        t1 += top[y]; t2 += top[y] * top[y];
        b1 += bot[y]; b2 += bot[y] * bot[y];
    }
    float i1 = 0.f, i2 = 0.f;
#pragma unroll
    for (int o = 0; o < 8; ++o) {
        i1 += I1p[((size_t)(b * 8 + o)) * 512 + x];
        i2 += I2p[((size_t)(b * 8 + o)) * 512 + x];
    }
    int lane = x & 63, wv = x >> 6;

    // template totals (64 partials -> wave 0)
    if (x < 64) {
        double d1 = tplS1p[x], d2 = tplS2p[x];
        for (int off = 32; off; off >>= 1) {
            d1 += __shfl_down(d1, off);
            d2 += __shfl_down(d2, off);
        }
        if (x == 0) { tS1s = d1; tS2s = d2; }
    }

    // frame total
    double tot = (double)i1 + (double)t1 + (double)b1;
    for (int off = 32; off; off >>= 1) tot += __shfl_down(tot, off);
    if (lane == 0) wrT[wv] = tot;

    // per-u column-window sums (register sliding), block totals + edge cols
    float s1 = i1 + t1, s2 = i2 + t2;
#pragma unroll
    for (int u = 0; u < NS; ++u) {
        if (u) {
            float a = top[u-1], c = bot[u-1];
            s1 += c - a;
            s2 += c * c - a * a;
        }
        double d1 = (double)s1, d2 = (double)s2;
        for (int off = 32; off; off >>= 1) {
            d1 += __shfl_down(d1, off);
            d2 += __shfl_down(d2, off);
        }
        if (lane == 0) { wr1[u][wv] = d1; wr2[u][wv] = d2; }
        if (x < 20)        { e1[u][x]       = s1; e2[u][x]       = s2; }
        else if (x >= 492) { e1[u][x - 472] = s1; e2[u][x - 472] = s2; }
    }
    __syncthreads();
    if (x == 0) {
        double s = 0.0;
        for (int i = 0; i < 8; ++i) s += wrT[i];
        sum1b = s;
    }
    if (x < NS) {
        double a = 0.0, c = 0.0;
        for (int i = 0; i < 8; ++i) { a += wr1[x][i]; c += wr2[x][i]; }
        totals1[x] = a; totals2[x] = c;
    }
    __syncthreads();
    if (x < NS * NS) {
        int u = x / NS, v = x - NS * u;
        double S1 = totals1[u], S2 = totals2[u];
        for (int j = 0; j < v; ++j)  { S1 -= (double)e1[u][j];      S2 -= (double)e2[u][j]; }
        for (int j = v; j < 20; ++j) { S1 -= (double)e1[u][20 + j]; S2 -= (double)e2[u][20 + j]; }
        const double inv = 1.0 / ((double)KWIN * (double)KWIN);
        double m1 = S1 * inv, m2 = S2 * inv;
        double var = m2 - (m1 * m1) * inv + 1e-8;   // reference's formula
        if (var < 0.0) var = 0.0;
        double tv = tS2s - tS1s * tS1s * (1.0 / (double)NPIX) + 1e-8;
        denomS[x] = (float)sqrt(tv * var);
    }
    __syncthreads();

    if (x < 64) {
        float corr = (float)(sum1b * tS1s * (1.0 / (double)NPIX));
        auto ccAt = [&](int m) -> float {
            int jj = ((m >> 4) * 512) + b * 16 + (m & 15);
            float s = 0.f;
#pragma unroll
            for (int o = 0; o < 8; ++o) s += cc8[(size_t)o * PARTSZ + jj];
            return s;
        };
        float best = -1e30f; int bidx = NS * NS;
        for (int i = x; i < NS * NS; i += 64) {
            float v = fabsf(ccAt(i) - corr) / denomS[i];
            if (v != v) v = 0.f;               // NaN -> 0 (matches reference)
            if (v > best) { best = v; bidx = i; }
        }
        for (int off = 32; off; off >>= 1) {
            float ov = __shfl_down(best, off);
            int   oi = __shfl_down(bidx, off);
            if (ov > best || (ov == best && oi < bidx)) { best = ov; bidx = oi; }
        }
        if (x == 0) {
            int shx = bidx / NS, shy = bidx % NS;
            auto nccAt = [&](int i, int j) -> float {
                i = (i < 0) ? i + NS : i; i = (i > NS - 1) ? NS - 1 : i;  // jnp wrap-then-clamp
                j = (j < 0) ? j + NS : j; j = (j > NS - 1) ? NS - 1 : j;
                float v = fabsf(ccAt(i * NS + j) - corr) / denomS[i * NS + j];
                if (v != v) v = 0.f;
                return v;
            };
            float lc  = logf(nccAt(shx, shy));
            float lxm = logf(nccAt(shx - 1, shy));
            float lxp = logf(nccAt(shx + 1, shy));
            float lym = logf(nccAt(shx, shy - 1));
            float lyp = logf(nccAt(shx, shy + 1));
            float shxn = -(float)(shx - 10) - (lxm - lxp) / (2.f * lxm - 4.f * lc + 2.f * lxp);
            float shyn = -(float)(shy - 10) - (lym - lyp) / (2.f * lym - 4.f * lc + 2.f * lyp);
            shifts[b]      = shxn;   // dy
            shifts[32 + b] = shyn;   // dx
        }
    }
}

// ---------------- Kernel B: bilinear warp + transposed write ----------------
__device__ __forceinline__ float samp(const float* __restrict__ img, int y, int x) {
    bool valid = (y >= 0) & (y < HH) & (x >= 0) & (x < WW);
    int yc = min(max(y, 0), HH - 1), xc = min(max(x, 0), WW - 1);
    float v = img[(size_t)yc * WW + xc];
    return valid ? v : 0.f;
}

__global__ __launch_bounds__(256) void warp_kernel(
    const float* __restrict__ fr, const float* __restrict__ shifts,
    float* __restrict__ out)
{
    int b  = blockIdx.z;
    int h0 = blockIdx.y * 32;
    int w0 = blockIdx.x * 32;
    float dy = shifts[b], dx = shifts[32 + b];
    const float* img = fr + (size_t)b * NPIX;
    __shared__ float tile[32][33];
    int tx = threadIdx.x & 31;
    int tz = threadIdx.x >> 5;
#pragma unroll
    for (int s = 0; s < 4; ++s) {
        int h = h0 + tz + 8 * s;
        int w = w0 + tx;
        float yq = (float)h - dy;
        float xq = (float)w - dx;
        float y0f = floorf(yq), x0f = floorf(xq);
        float wy = yq - y0f, wx = xq - x0f;
        int y0 = (int)y0f, x0 = (int)x0f;
        float v00 = samp(img, y0,     x0);
        float v01 = samp(img, y0,     x0 + 1);
        float v10 = samp(img, y0 + 1, x0);
        float v11 = samp(img, y0 + 1, x0 + 1);
        float val = v00 * (1.f - wy) * (1.f - wx) + v01 * (1.f - wy) * wx
                  + v10 * wy * (1.f - wx)         + v11 * wy * wx;
        tile[tz + 8 * s][tx] = val;
    }
    __syncthreads();
#pragma unroll
    for (int s = 0; s < 4; ++s) {
        int hh = tx;
        int ww = tz + 8 * s;
        out[(size_t)b * NPIX + (size_t)(w0 + ww) * HH + (h0 + hh)] = tile[hh][ww];
    }
}

// ---------------- launch ----------------------------------------------------
extern "C" void kernel_launch(void* const* d_in, const int* in_sizes, int n_in,
                              void* d_out, int out_size, void* d_ws, size_t ws_size,
                              hipStream_t stream) {
    const float* fr  = (const float*)d_in[0];   // (1,32,512,512,1) flat
    const float* tpl = (const float*)d_in[1];   // (512,512)
    float* out = (float*)d_out;
    char* ws = (char*)d_ws;

    // ws layout (~23 MB), every buffer fully rewritten each launch -> no memset
    unsigned short* tplb = (unsigned short*)(ws + 0);        // 1.11 MB (2 copies)
    float*  I1p    = (float*) (ws + 2097152);                // 512 KB (256*512 f)
    float*  I2p    = (float*) (ws + 2621440);                // 512 KB
    double* tplS1p = (double*)(ws + 3145728);                // 512 B
    double* tplS2p = (double*)(ws + 3146240);                // 512 B
    float*  shifts = (float*) (ws + 3146752);                // 256 B
    float*  cc8    = (float*) (ws + 4194304);                // 458 KB
    float*  part   = (float*) (ws + 8388608);                // 14.68 MB (256 chunks)

    prep      <<<448, 512, 0, stream>>>(fr, tpl, tplb, I1p, I2p, tplS1p, tplS2p);
    corr_mfma <<<256, 896, 0, stream>>>(fr, tplb, part);
    reduce_k  <<<224, 512, 0, stream>>>(part, cc8);
    stage2_am <<<32, 512, 0, stream>>>(cc8, fr, I1p, I2p, tplS1p, tplS2p, shifts);
    warp_kernel<<<dim3(16, 16, 32), 256, 0, stream>>>(fr, shifts, out);
}

// Round 14
// 155.242 us; speedup vs baseline: 1.1068x; 1.1068x over previous
//
#include <hip/hip_runtime.h>
#include <math.h>

#define HH 512
#define WW 512
#define NPIX (HH*WW)
#define NB 32
#define NS 21           // 2*MS+1 shifts per axis
#define KWIN 492        // window size (H - 2*10)
#define NKB 512         // split-K chunks (512 k each)
#define MT28 28         // m-tiles (448 = 28*16, M=441 padded)
#define PARTSZ (MT28*32*16)   // 14336 floats per k-chunk
#define TPLB_COPY 278528      // 512*544 shorts per parity copy

typedef __attribute__((ext_vector_type(8))) short short8;
typedef __attribute__((ext_vector_type(4))) float floatx4;

__device__ __forceinline__ unsigned short f2bf(float f) {
    unsigned u = __float_as_uint(f);
    unsigned r = (u + 0x7fffu + ((u >> 16) & 1u)) >> 16;
    return (unsigned short)r;
}

// 16B fragment load from a 4B-aligned address (tplb cols are even, not x8).
__device__ __forceinline__ short8 loadA(const unsigned short* p) {
    union { short8 v; unsigned u[4]; } r;
    const unsigned* q = (const unsigned*)p;
    r.u[0] = q[0]; r.u[1] = q[1]; r.u[2] = q[2]; r.u[3] = q[3];
    return r.v;
}

// ---------------- prep: interior col partial sums (256 blk), template partial
//   sums (64 blk), padded bf16 template (128 blk). No atomics, no flag.
__global__ __launch_bounds__(512) void prep(
    const float* __restrict__ fr, const float* __restrict__ tpl,
    unsigned short* __restrict__ tplb,
    float* __restrict__ I1p, float* __restrict__ I2p,
    double* __restrict__ tplS1p, double* __restrict__ tplS2p)
{
    int blk = blockIdx.x;
    int t   = threadIdx.x;

    if (blk < 256) {
        // interior column partial sums: (frame b, row-oct) -> I1p/I2p
        int b = blk >> 3, oct = blk & 7;              // b in [0,32)
        const float* img = fr + (size_t)b * NPIX;
        int x = t;
        float s1 = 0.f, s2 = 0.f;
        int y0 = 20 + 59 * oct;                       // rows 20..491 = 8*59
        for (int y = y0; y < y0 + 59; ++y) {
            float v = img[(size_t)y * WW + x];
            s1 += v; s2 += v * v;
        }
        I1p[(size_t)blk * 512 + x] = s1;
        I2p[(size_t)blk * 512 + x] = s2;
    } else if (blk < 320) {
        // template partial sums: 64 jobs of 8 rows
        __shared__ double jb1[8], jb2[8];
        int tj = blk - 256;
        const float* trow = tpl + (size_t)tj * 8 * WW;
        float s1 = 0.f, s2 = 0.f;
        int x = t;
        for (int y = 0; y < 8; ++y) {
            float v = trow[(size_t)y * WW + x];
            s1 += v; s2 += v * v;
        }
        double d1 = (double)s1, d2 = (double)s2;
        for (int off = 32; off; off >>= 1) {
            d1 += __shfl_down(d1, off);
            d2 += __shfl_down(d2, off);
        }
        int lane = t & 63, wv = t >> 6;
        if (lane == 0) { jb1[wv] = d1; jb2[wv] = d2; }
        __syncthreads();
        if (t == 0) {
            double a = 0.0, c = 0.0;
            for (int i = 0; i < 8; ++i) { a += jb1[i]; c += jb2[i]; }
            tplS1p[tj] = a; tplS2p[tj] = c;
        }
    } else {
        // padded bf16 template: copyP[sy][c] = bf16(tpl[sy][(c-16-P) mod 512])
        int sy0 = (blk - 320) * 4;                    // 128 blocks x 4 rows
#pragma unroll
        for (int rr = 0; rr < 4; ++rr) {
            int sy = sy0 + rr;
            const float* srow = tpl + (size_t)sy * WW;
#pragma unroll
            for (int P = 0; P < 2; ++P) {
                for (int c = t; c < 544; c += 512) {
                    int sx = (c + 496 - P) & 511;     // (c-16-P) mod 512
                    tplb[(size_t)P * TPLB_COPY + (size_t)sy * 544 + c] = f2bf(srow[sx]);
                }
            }
        }
    }
}

// ---------------- Kernel C: implicit-GEMM correlation via MFMA --------------
// REVERTED to the R7 structure (fastest measured: ~12 us): 512 chunks of
// 512 k, ONE block per chunk, 896 thr = 14 waves x 2 m-tiles, single 32 KB
// Bs, load->convert->LDS immediately (no register staging -> no spills;
// R12/R13's T14 register staging spilled ~100 MB and ran 48-52 us).
// 2 blocks/CU co-resident: the other block's MFMA hides this block's
// staging latency + barrier drains. A fragments from the 1.1 MB padded
// template (L2-hot): tplb[P=dv&1][(kb+522-du)&511][x - dv + 26 + P].
__global__ __launch_bounds__(896) void corr_mfma(
    const float* __restrict__ fr,
    const unsigned short* __restrict__ tplb,
    float* __restrict__ part)
{
    __shared__ unsigned short Bs[16384];   // [k8][frame][8] : 512k x 32fr, 32 KB

    const int t   = threadIdx.x;
    const int l   = t & 63;
    const int wid = t >> 6;               // wave 0..13 = tile-pair
    const int idx = blockIdx.x;           // 0..511
    const int kb  = ((idx & 7) << 6) | (idx >> 3);   // XCD swizzle (64/XCD)
    const int k0  = kb << 9;              // k-chunk base (512 each)
    const int kg  = l >> 4;               // k-group 0..3
    const int ln  = l & 15;

    // fused conv: fr slice -> bf16 interleave in LDS (coalesced 16B loads)
    for (int i = t; i < 4096; i += 896) {
        int frame = i >> 7, q = i & 127;
        float4 v = *(const float4*)(fr + (size_t)frame * NPIX + k0 + 4 * q);
        int k8 = q >> 1, j4 = (q & 1) * 4;
        ushort4 o;
        o.x = f2bf(v.x); o.y = f2bf(v.y); o.z = f2bf(v.z); o.w = f2bf(v.w);
        *(ushort4*)&Bs[(k8 * 32 + frame) * 8 + j4] = o;
    }

    const unsigned short* pA0;
    const unsigned short* pA1;
    {
        int m_g = 32 * wid + ln;           // mt = 0
        int du  = (m_g * 1561) >> 15;      // m_g/21 exact for m_g<=447
        int dv  = m_g - 21 * du;
        if (m_g >= 441) { du = 0; dv = 0; }   // pad rows: loaded, never used
        int P   = dv & 1;
        pA0 = tplb + (size_t)P * TPLB_COPY
            + (size_t)((kb + 522 - du) & 511) * 544 + (8 * kg - dv + 26 + P);
        m_g = 32 * wid + 16 + ln;          // mt = 1
        du  = (m_g * 1561) >> 15;
        dv  = m_g - 21 * du;
        if (m_g >= 441) { du = 0; dv = 0; }
        P   = dv & 1;
        pA1 = tplb + (size_t)P * TPLB_COPY
            + (size_t)((kb + 522 - du) & 511) * 544 + (8 * kg - dv + 26 + P);
    }

    const unsigned short* lB = Bs + kg * 256 + ln * 8;

    __syncthreads();

    floatx4 acc00 = {}, acc01 = {}, acc10 = {}, acc11 = {};

#pragma unroll
    for (int ks = 0; ks < 16; ++ks) {      // 16 steps x 32 k = 512
        short8 A0 = loadA(pA0);
        short8 A1 = loadA(pA1);
        short8 B0 = *(const short8*)(lB + ks * 1024);         // frames 0..15
        short8 B1 = *(const short8*)(lB + ks * 1024 + 128);   // frames 16..31
        acc00 = __builtin_amdgcn_mfma_f32_16x16x32_bf16(A0, B0, acc00, 0, 0, 0);
        acc01 = __builtin_amdgcn_mfma_f32_16x16x32_bf16(A0, B1, acc01, 0, 0, 0);
        acc10 = __builtin_amdgcn_mfma_f32_16x16x32_bf16(A1, B0, acc10, 0, 0, 0);
        acc11 = __builtin_amdgcn_mfma_f32_16x16x32_bf16(A1, B1, acc11, 0, 0, 0);
        pA0 += 32; pA1 += 32;
    }

    // dense partial stores: part[((kb*28 + mtile)*32 + n)*16 + mr], mr=4kg+r
    {
        size_t base = ((size_t)kb * MT28 + 2 * wid) * 32;
        floatx4* p;
        p = (floatx4*)(part + (base + ln)      * 16 + 4 * kg); *p = acc00;
        p = (floatx4*)(part + (base + 16 + ln) * 16 + 4 * kg); *p = acc01;
        p = (floatx4*)(part + (base + 32 + ln) * 16 + 4 * kg); *p = acc10;
        p = (floatx4*)(part + (base + 48 + ln) * 16 + 4 * kg); *p = acc11;
    }
}

// ---------------- reduce: part (512 k-chunks) -> cc8 (8 oct partials) -------
// 224 blocks x 512. Disjoint writes, no atomics. Kernel boundary provides
// cross-XCD visibility to stage2_am (no flag/spin).
__global__ __launch_bounds__(512) void reduce_k(
    const float* __restrict__ part, float* __restrict__ cc8)
{
    int blk = blockIdx.x;
    int oct = blk / 28;                      // 0..7 (64 kb-chunks each)
    int j   = (blk % 28) * 512 + threadIdx.x;
    const float* p = part + (size_t)(oct * 64) * PARTSZ + j;
    float s = 0.f;
#pragma unroll 8
    for (int i = 0; i < 64; ++i)
        s += p[(size_t)i * PARTSZ];
    cc8[(size_t)oct * PARTSZ + j] = s;
}

// ---------------- stage2 + argmax + subpixel: 32 blocks (one per frame) -----
__global__ __launch_bounds__(512) void stage2_am(
    const float* __restrict__ cc8, const float* __restrict__ fr,
    const float* __restrict__ I1p, const float* __restrict__ I2p,
    const double* __restrict__ tplS1p, const double* __restrict__ tplS2p,
    float* __restrict__ shifts)
{
    __shared__ double wr1[NS][8], wr2[NS][8], wrT[8];
    __shared__ float  e1[NS][40], e2[NS][40];
    __shared__ double totals1[NS], totals2[NS];
    __shared__ float  denomS[NS * NS];
    __shared__ double tS1s, tS2s, sum1b;

    int b = blockIdx.x;
    int x = threadIdx.x;
    const float* img = fr + (size_t)b * NPIX;
    float top[20], bot[20];
#pragma unroll
    for (int y = 0; y < 20; ++y) top[y] = img[(size_t)y * WW + x];
#pragma unroll
    for (int y = 0; y < 20; ++y) bot[y] = img[(size_t)(492 + y) * WW + x];

    float t1 = 0.f, t2 = 0.f, b1 = 0.f, b2 = 0.f;
#pragma unroll
    for (int y = 0; y < 20; ++y) {
        t1 += top[y]; t2 += top[y] * top[y];
        b1 += bot[y]; b2 += bot[y] * bot[y];
    }
    float i1 = 0.f, i2 = 0.f;
#pragma unroll
    for (int o = 0; o < 8; ++o) {
        i1 += I1p[((size_t)(b * 8 + o)) * 512 + x];
        i2 += I2p[((size_t)(b * 8 + o)) * 512 + x];
    }
    int lane = x & 63, wv = x >> 6;

    // template totals (64 partials -> wave 0)
    if (x < 64) {
        double d1 = tplS1p[x], d2 = tplS2p[x];
        for (int off = 32; off; off >>= 1) {
            d1 += __shfl_down(d1, off);
            d2 += __shfl_down(d2, off);
        }
        if (x == 0) { tS1s = d1; tS2s = d2; }
    }

    // frame total
    double tot = (double)i1 + (double)t1 + (double)b1;
    for (int off = 32; off; off >>= 1) tot += __shfl_down(tot, off);
    if (lane == 0) wrT[wv] = tot;

    // per-u column-window sums (register sliding), block totals + edge cols
    float s1 = i1 + t1, s2 = i2 + t2;
#pragma unroll
    for (int u = 0; u < NS; ++u) {
        if (u) {
            float a = top[u-1], c = bot[u-1];
            s1 += c - a;
            s2 += c * c - a * a;
        }
        double d1 = (double)s1, d2 = (double)s2;
        for (int off = 32; off; off >>= 1) {
            d1 += __shfl_down(d1, off);
            d2 += __shfl_down(d2, off);
        }
        if (lane == 0) { wr1[u][wv] = d1; wr2[u][wv] = d2; }
        if (x < 20)        { e1[u][x]       = s1; e2[u][x]       = s2; }
        else if (x >= 492) { e1[u][x - 472] = s1; e2[u][x - 472] = s2; }
    }
    __syncthreads();
    if (x == 0) {
        double s = 0.0;
        for (int i = 0; i < 8; ++i) s += wrT[i];
        sum1b = s;
    }
    if (x < NS) {
        double a = 0.0, c = 0.0;
        for (int i = 0; i < 8; ++i) { a += wr1[x][i]; c += wr2[x][i]; }
        totals1[x] = a; totals2[x] = c;
    }
    __syncthreads();
    if (x < NS * NS) {
        int u = x / NS, v = x - NS * u;
        double S1 = totals1[u], S2 = totals2[u];
        for (int j = 0; j < v; ++j)  { S1 -= (double)e1[u][j];      S2 -= (double)e2[u][j]; }
        for (int j = v; j < 20; ++j) { S1 -= (double)e1[u][20 + j]; S2 -= (double)e2[u][20 + j]; }
        const double inv = 1.0 / ((double)KWIN * (double)KWIN);
        double m1 = S1 * inv, m2 = S2 * inv;
        double var = m2 - (m1 * m1) * inv + 1e-8;   // reference's formula
        if (var < 0.0) var = 0.0;
        double tv = tS2s - tS1s * tS1s * (1.0 / (double)NPIX) + 1e-8;
        denomS[x] = (float)sqrt(tv * var);
    }
    __syncthreads();

    if (x < 64) {
        float corr = (float)(sum1b * tS1s * (1.0 / (double)NPIX));
        auto ccAt = [&](int m) -> float {
            int jj = ((m >> 4) * 512) + b * 16 + (m & 15);
            float s = 0.f;
#pragma unroll
            for (int o = 0; o < 8; ++o) s += cc8[(size_t)o * PARTSZ + jj];
            return s;
        };
        float best = -1e30f; int bidx = NS * NS;
        for (int i = x; i < NS * NS; i += 64) {
            float v = fabsf(ccAt(i) - corr) / denomS[i];
            if (v != v) v = 0.f;               // NaN -> 0 (matches reference)
            if (v > best) { best = v; bidx = i; }
        }
        for (int off = 32; off; off >>= 1) {
            float ov = __shfl_down(best, off);
            int   oi = __shfl_down(bidx, off);
            if (ov > best || (ov == best && oi < bidx)) { best = ov; bidx = oi; }
        }
        if (x == 0) {
            int shx = bidx / NS, shy = bidx % NS;
            auto nccAt = [&](int i, int j) -> float {
                i = (i < 0) ? i + NS : i; i = (i > NS - 1) ? NS - 1 : i;  // jnp wrap-then-clamp
                j = (j < 0) ? j + NS : j; j = (j > NS - 1) ? NS - 1 : j;
                float v = fabsf(ccAt(i * NS + j) - corr) / denomS[i * NS + j];
                if (v != v) v = 0.f;
                return v;
            };
            float lc  = logf(nccAt(shx, shy));
            float lxm = logf(nccAt(shx - 1, shy));
            float lxp = logf(nccAt(shx + 1, shy));
            float lym = logf(nccAt(shx, shy - 1));
            float lyp = logf(nccAt(shx, shy + 1));
            float shxn = -(float)(shx - 10) - (lxm - lxp) / (2.f * lxm - 4.f * lc + 2.f * lxp);
            float shyn = -(float)(shy - 10) - (lym - lyp) / (2.f * lym - 4.f * lc + 2.f * lyp);
            shifts[b]      = shxn;   // dy
            shifts[32 + b] = shyn;   // dx
        }
    }
}

// ---------------- Kernel B: bilinear warp + transposed write ----------------
__device__ __forceinline__ float samp(const float* __restrict__ img, int y, int x) {
    bool valid = (y >= 0) & (y < HH) & (x >= 0) & (x < WW);
    int yc = min(max(y, 0), HH - 1), xc = min(max(x, 0), WW - 1);
    float v = img[(size_t)yc * WW + xc];
    return valid ? v : 0.f;
}

__global__ __launch_bounds__(256) void warp_kernel(
    const float* __restrict__ fr, const float* __restrict__ shifts,
    float* __restrict__ out)
{
    int b  = blockIdx.z;
    int h0 = blockIdx.y * 32;
    int w0 = blockIdx.x * 32;
    float dy = shifts[b], dx = shifts[32 + b];
    const float* img = fr + (size_t)b * NPIX;
    __shared__ float tile[32][33];
    int tx = threadIdx.x & 31;
    int tz = threadIdx.x >> 5;
#pragma unroll
    for (int s = 0; s < 4; ++s) {
        int h = h0 + tz + 8 * s;
        int w = w0 + tx;
        float yq = (float)h - dy;
        float xq = (float)w - dx;
        float y0f = floorf(yq), x0f = floorf(xq);
        float wy = yq - y0f, wx = xq - x0f;
        int y0 = (int)y0f, x0 = (int)x0f;
        float v00 = samp(img, y0,     x0);
        float v01 = samp(img, y0,     x0 + 1);
        float v10 = samp(img, y0 + 1, x0);
        float v11 = samp(img, y0 + 1, x0 + 1);
        float val = v00 * (1.f - wy) * (1.f - wx) + v01 * (1.f - wy) * wx
                  + v10 * wy * (1.f - wx)         + v11 * wy * wx;
        tile[tz + 8 * s][tx] = val;
    }
    __syncthreads();
#pragma unroll
    for (int s = 0; s < 4; ++s) {
        int hh = tx;
        int ww = tz + 8 * s;
        out[(size_t)b * NPIX + (size_t)(w0 + ww) * HH + (h0 + hh)] = tile[hh][ww];
    }
}

// ---------------- launch ----------------------------------------------------
extern "C" void kernel_launch(void* const* d_in, const int* in_sizes, int n_in,
                              void* d_out, int out_size, void* d_ws, size_t ws_size,
                              hipStream_t stream) {
    const float* fr  = (const float*)d_in[0];   // (1,32,512,512,1) flat
    const float* tpl = (const float*)d_in[1];   // (512,512)
    float* out = (float*)d_out;
    char* ws = (char*)d_ws;

    // ws layout (~39 MB), every buffer fully rewritten each launch -> no memset
    unsigned short* tplb = (unsigned short*)(ws + 0);        // 1.11 MB (2 copies)
    float*  I1p    = (float*) (ws + 2097152);                // 512 KB (256*512 f)
    float*  I2p    = (float*) (ws + 2621440);                // 512 KB
    double* tplS1p = (double*)(ws + 3145728);                // 512 B
    double* tplS2p = (double*)(ws + 3146240);                // 512 B
    float*  shifts = (float*) (ws + 3146752);                // 256 B
    float*  cc8    = (float*) (ws + 4194304);                // 458 KB
    float*  part   = (float*) (ws + 8388608);                // 29.36 MB (512 chunks)

    prep      <<<448, 512, 0, stream>>>(fr, tpl, tplb, I1p, I2p, tplS1p, tplS2p);
    corr_mfma <<<512, 896, 0, stream>>>(fr, tplb, part);
    reduce_k  <<<224, 512, 0, stream>>>(part, cc8);
    stage2_am <<<32, 512, 0, stream>>>(cc8, fr, I1p, I2p, tplS1p, tplS2p, shifts);
    warp_kernel<<<dim3(16, 16, 32), 256, 0, stream>>>(fr, shifts, out);
}

// Round 15
// 147.309 us; speedup vs baseline: 1.1664x; 1.0539x over previous
//
#include <hip/hip_runtime.h>
#include <math.h>

#define HH 512
#define WW 512
#define NPIX (HH*WW)
#define NB 32
#define NS 21           // 2*MS+1 shifts per axis
#define KWIN 492        // window size (H - 2*10)
#define NKB 256         // split-K chunks (1024 k each)
#define MT28 28         // m-tiles (448 = 28*16, M=441 padded)
#define PARTSZ (MT28*32*16)   // 14336 floats per k-chunk
#define TPLB_COPY 278528      // 512*544 shorts per parity copy

typedef __attribute__((ext_vector_type(8))) short short8;
typedef __attribute__((ext_vector_type(4))) float floatx4;

__device__ __forceinline__ unsigned short f2bf(float f) {
    unsigned u = __float_as_uint(f);
    unsigned r = (u + 0x7fffu + ((u >> 16) & 1u)) >> 16;
    return (unsigned short)r;
}

// 16B fragment load from a 4B-aligned address (tplb cols are even, not x8).
__device__ __forceinline__ short8 loadA(const unsigned short* p) {
    union { short8 v; unsigned u[4]; } r;
    const unsigned* q = (const unsigned*)p;
    r.u[0] = q[0]; r.u[1] = q[1]; r.u[2] = q[2]; r.u[3] = q[3];
    return r.v;
}

// ---------------- prep_tpl: padded bf16 template only (128 blocks) ----------
// copyP[sy][c] = bf16(tpl[sy][(c-16-P) mod 512]); ~1 MB read, ~2 us.
__global__ __launch_bounds__(512) void prep_tpl(
    const float* __restrict__ tpl, unsigned short* __restrict__ tplb)
{
    int t   = threadIdx.x;
    int sy0 = blockIdx.x * 4;                         // 128 blocks x 4 rows
#pragma unroll
    for (int rr = 0; rr < 4; ++rr) {
        int sy = sy0 + rr;
        const float* srow = tpl + (size_t)sy * WW;
#pragma unroll
        for (int P = 0; P < 2; ++P) {
            for (int c = t; c < 544; c += 512) {
                int sx = (c + 496 - P) & 511;         // (c-16-P) mod 512
                tplb[(size_t)P * TPLB_COPY + (size_t)sy * 544 + c] = f2bf(srow[sx]);
            }
        }
    }
}

// ---------------- Kernel C: corr MFMA + fused prep sums ---------------------
// blocks [0,256):   R10's corr (best measured): NKB=256 chunks of 1024 k,
//                   896 thr = 14 waves x 2 m-tiles, two 512-k sub-chunks
//                   staged into LDS sequentially, accumulating in registers.
//                   part stays 14.7 MB (minimum traffic).
// blocks [256,512): interior column partial sums (frame b, row-oct), t<512.
// blocks [512,576): template partial sums (64 jobs of 8 rows), t<512.
// The 320 sum blocks co-schedule onto the 2nd block-slot per CU: their 30 MB
// fr read overlaps corr's compute, and corr gains co-resident waves (TLP).
__global__ __launch_bounds__(896) void corr_mfma(
    const float* __restrict__ fr, const unsigned short* __restrict__ tplb,
    const float* __restrict__ tpl, float* __restrict__ part,
    float* __restrict__ I1p, float* __restrict__ I2p,
    double* __restrict__ tplS1p, double* __restrict__ tplS2p)
{
    __shared__ unsigned short Bs[16384];   // 32 KB (corr branch)
    __shared__ double jb1[8], jb2[8];      // template-sum branch

    const int blk = blockIdx.x;
    const int t   = threadIdx.x;

    if (blk >= 512) {                      // template partial sums
        int tj = blk - 512;
        if (t < 512) {
            const float* trow = tpl + (size_t)tj * 8 * WW;
            float s1 = 0.f, s2 = 0.f;
            for (int y = 0; y < 8; ++y) {
                float v = trow[(size_t)y * WW + t];
                s1 += v; s2 += v * v;
            }
            double d1 = (double)s1, d2 = (double)s2;
            for (int off = 32; off; off >>= 1) {
                d1 += __shfl_down(d1, off);
                d2 += __shfl_down(d2, off);
            }
            int lane = t & 63, wv = t >> 6;
            if (lane == 0) { jb1[wv] = d1; jb2[wv] = d2; }
        }
        __syncthreads();
        if (t == 0) {
            double a = 0.0, c = 0.0;
            for (int i = 0; i < 8; ++i) { a += jb1[i]; c += jb2[i]; }
            tplS1p[tj] = a; tplS2p[tj] = c;
        }
        return;
    }
    if (blk >= 256) {                      // interior column partial sums
        if (t < 512) {
            int id = blk - 256;
            int b = id >> 3, oct = id & 7;
            const float* img = fr + (size_t)b * NPIX;
            float s1 = 0.f, s2 = 0.f;
            int y0 = 20 + 59 * oct;                   // rows 20..491 = 8*59
            for (int y = y0; y < y0 + 59; ++y) {
                float v = img[(size_t)y * WW + t];
                s1 += v; s2 += v * v;
            }
            I1p[(size_t)id * 512 + t] = s1;
            I2p[(size_t)id * 512 + t] = s2;
        }
        return;
    }

    // ---------------- corr branch (identical to R10) ------------------------
    const int l   = t & 63;
    const int wid = t >> 6;               // wave 0..13 = tile-pair
    const int idx = blk;                  // 0..255
    const int kb  = ((idx & 7) << 5) | (idx >> 3);   // XCD swizzle (32/XCD)
    const int kg  = l >> 4;               // k-group 0..3
    const int ln  = l & 15;

    int du0, dv0, du1, dv1;
    {
        int m_g = 32 * wid + ln;           // mt = 0
        du0 = (m_g * 1561) >> 15;          // m_g/21 exact for m_g<=447
        dv0 = m_g - 21 * du0;
        if (m_g >= 441) { du0 = 0; dv0 = 0; }   // pad rows: loaded, never used
        m_g = 32 * wid + 16 + ln;          // mt = 1
        du1 = (m_g * 1561) >> 15;
        dv1 = m_g - 21 * du1;
        if (m_g >= 441) { du1 = 0; dv1 = 0; }
    }
    const int P0 = dv0 & 1, P1 = dv1 & 1;
    const int col0 = 8 * kg - dv0 + 26 + P0;
    const int col1 = 8 * kg - dv1 + 26 + P1;

    const unsigned short* lB = Bs + kg * 256 + ln * 8;

    floatx4 acc00 = {}, acc01 = {}, acc10 = {}, acc11 = {};

#pragma unroll 1
    for (int c = 0; c < 2; ++c) {
        const int row = 2 * kb + c;          // template/frame image row
        const int k0  = row << 9;            // global k base of this sub-chunk
        if (c) __syncthreads();              // WAR on Bs
        for (int i = t; i < 4096; i += 896) {
            int frame = i >> 7, q = i & 127;
            float4 v = *(const float4*)(fr + (size_t)frame * NPIX + k0 + 4 * q);
            int k8 = q >> 1, j4 = (q & 1) * 4;
            ushort4 o;
            o.x = f2bf(v.x); o.y = f2bf(v.y); o.z = f2bf(v.z); o.w = f2bf(v.w);
            *(ushort4*)&Bs[(k8 * 32 + frame) * 8 + j4] = o;
        }
        __syncthreads();

        const unsigned short* pA0 = tplb + (size_t)P0 * TPLB_COPY
            + (size_t)((row + 522 - du0) & 511) * 544 + col0;
        const unsigned short* pA1 = tplb + (size_t)P1 * TPLB_COPY
            + (size_t)((row + 522 - du1) & 511) * 544 + col1;

#pragma unroll
        for (int ks = 0; ks < 16; ++ks) {    // 16 steps x 32 k = 512
            short8 A0 = loadA(pA0);
            short8 A1 = loadA(pA1);
            short8 B0 = *(const short8*)(lB + ks * 1024);         // frames 0..15
            short8 B1 = *(const short8*)(lB + ks * 1024 + 128);   // frames 16..31
            acc00 = __builtin_amdgcn_mfma_f32_16x16x32_bf16(A0, B0, acc00, 0, 0, 0);
            acc01 = __builtin_amdgcn_mfma_f32_16x16x32_bf16(A0, B1, acc01, 0, 0, 0);
            acc10 = __builtin_amdgcn_mfma_f32_16x16x32_bf16(A1, B0, acc10, 0, 0, 0);
            acc11 = __builtin_amdgcn_mfma_f32_16x16x32_bf16(A1, B1, acc11, 0, 0, 0);
            pA0 += 32; pA1 += 32;
        }
    }

    // dense partial stores: part[((kb*28 + mtile)*32 + n)*16 + mr], mr=4kg+r
    {
        size_t base = ((size_t)kb * MT28 + 2 * wid) * 32;
        floatx4* p;
        p = (floatx4*)(part + (base + ln)      * 16 + 4 * kg); *p = acc00;
        p = (floatx4*)(part + (base + 16 + ln) * 16 + 4 * kg); *p = acc01;
        p = (floatx4*)(part + (base + 32 + ln) * 16 + 4 * kg); *p = acc10;
        p = (floatx4*)(part + (base + 48 + ln) * 16 + 4 * kg); *p = acc11;
    }
}

// ---------------- reduce: part (256 k-chunks) -> cc8 (8 oct partials) -------
// 224 blocks x 512. Disjoint writes, no atomics. Kernel boundary provides
// cross-XCD visibility to stage2_am (no flag/spin).
__global__ __launch_bounds__(512) void reduce_k(
    const float* __restrict__ part, float* __restrict__ cc8)
{
    int blk = blockIdx.x;
    int oct = blk / 28;                      // 0..7 (32 kb-chunks each)
    int j   = (blk % 28) * 512 + threadIdx.x;
    const float* p = part + (size_t)(oct * 32) * PARTSZ + j;
    float s = 0.f;
#pragma unroll 8
    for (int i = 0; i < 32; ++i)
        s += p[(size_t)i * PARTSZ];
    cc8[(size_t)oct * PARTSZ + j] = s;
}

// ---------------- stage2 + argmax + subpixel: 32 blocks (one per frame) -----
__global__ __launch_bounds__(512) void stage2_am(
    const float* __restrict__ cc8, const float* __restrict__ fr,
    const float* __restrict__ I1p, const float* __restrict__ I2p,
    const double* __restrict__ tplS1p, const double* __restrict__ tplS2p,
    float* __restrict__ shifts)
{
    __shared__ double wr1[NS][8], wr2[NS][8], wrT[8];
    __shared__ float  e1[NS][40], e2[NS][40];
    __shared__ double totals1[NS], totals2[NS];
    __shared__ float  denomS[NS * NS];
    __shared__ double tS1s, tS2s, sum1b;

    int b = blockIdx.x;
    int x = threadIdx.x;
    const float* img = fr + (size_t)b * NPIX;
    float top[20], bot[20];
#pragma unroll
    for (int y = 0; y < 20; ++y) top[y] = img[(size_t)y * WW + x];
#pragma unroll
    for (int y = 0; y < 20; ++y) bot[y] = img[(size_t)(492 + y) * WW + x];

    float t1 = 0.f, t2 = 0.f, b1 = 0.f, b2 = 0.f;
#pragma unroll
    for (int y = 0; y < 20; ++y) {
        t1 += top[y]; t2 += top[y] * top[y];
        b1 += bot[y]; b2 += bot[y] * bot[y];
    }
    float i1 = 0.f, i2 = 0.f;
#pragma unroll
    for (int o = 0; o < 8; ++o) {
        i1 += I1p[((size_t)(b * 8 + o)) * 512 + x];
        i2 += I2p[((size_t)(b * 8 + o)) * 512 + x];
    }
    int lane = x & 63, wv = x >> 6;

    // template totals (64 partials -> wave 0)
    if (x < 64) {
        double d1 = tplS1p[x], d2 = tplS2p[x];
        for (int off = 32; off; off >>= 1) {
            d1 += __shfl_down(d1, off);
            d2 += __shfl_down(d2, off);
        }
        if (x == 0) { tS1s = d1; tS2s = d2; }
    }

    // frame total
    double tot = (double)i1 + (double)t1 + (double)b1;
    for (int off = 32; off; off >>= 1) tot += __shfl_down(tot, off);
    if (lane == 0) wrT[wv] = tot;

    // per-u column-window sums (register sliding), block totals + edge cols
    float s1 = i1 + t1, s2 = i2 + t2;
#pragma unroll
    for (int u = 0; u < NS; ++u) {
        if (u) {
            float a = top[u-1], c = bot[u-1];
            s1 += c - a;
            s2 += c * c - a * a;
        }
        double d1 = (double)s1, d2 = (double)s2;
        for (int off = 32; off; off >>= 1) {
            d1 += __shfl_down(d1, off);
            d2 += __shfl_down(d2, off);
        }
        if (lane == 0) { wr1[u][wv] = d1; wr2[u][wv] = d2; }
        if (x < 20)        { e1[u][x]       = s1; e2[u][x]       = s2; }
        else if (x >= 492) { e1[u][x - 472] = s1; e2[u][x - 472] = s2; }
    }
    __syncthreads();
    if (x == 0) {
        double s = 0.0;
        for (int i = 0; i < 8; ++i) s += wrT[i];
        sum1b = s;
    }
    if (x < NS) {
        double a = 0.0, c = 0.0;
        for (int i = 0; i < 8; ++i) { a += wr1[x][i]; c += wr2[x][i]; }
        totals1[x] = a; totals2[x] = c;
    }
    __syncthreads();
    if (x < NS * NS) {
        int u = x / NS, v = x - NS * u;
        double S1 = totals1[u], S2 = totals2[u];
        for (int j = 0; j < v; ++j)  { S1 -= (double)e1[u][j];      S2 -= (double)e2[u][j]; }
        for (int j = v; j < 20; ++j) { S1 -= (double)e1[u][20 + j]; S2 -= (double)e2[u][20 + j]; }
        const double inv = 1.0 / ((double)KWIN * (double)KWIN);
        double m1 = S1 * inv, m2 = S2 * inv;
        double var = m2 - (m1 * m1) * inv + 1e-8;   // reference's formula
        if (var < 0.0) var = 0.0;
        double tv = tS2s - tS1s * tS1s * (1.0 / (double)NPIX) + 1e-8;
        denomS[x] = (float)sqrt(tv * var);
    }
    __syncthreads();

    if (x < 64) {
        float corr = (float)(sum1b * tS1s * (1.0 / (double)NPIX));
        auto ccAt = [&](int m) -> float {
            int jj = ((m >> 4) * 512) + b * 16 + (m & 15);
            float s = 0.f;
#pragma unroll
            for (int o = 0; o < 8; ++o) s += cc8[(size_t)o * PARTSZ + jj];
            return s;
        };
        float best = -1e30f; int bidx = NS * NS;
        for (int i = x; i < NS * NS; i += 64) {
            float v = fabsf(ccAt(i) - corr) / denomS[i];
            if (v != v) v = 0.f;               // NaN -> 0 (matches reference)
            if (v > best) { best = v; bidx = i; }
        }
        for (int off = 32; off; off >>= 1) {
            float ov = __shfl_down(best, off);
            int   oi = __shfl_down(bidx, off);
            if (ov > best || (ov == best && oi < bidx)) { best = ov; bidx = oi; }
        }
        if (x == 0) {
            int shx = bidx / NS, shy = bidx % NS;
            auto nccAt = [&](int i, int j) -> float {
                i = (i < 0) ? i + NS : i; i = (i > NS - 1) ? NS - 1 : i;  // jnp wrap-then-clamp
                j = (j < 0) ? j + NS : j; j = (j > NS - 1) ? NS - 1 : j;
                float v = fabsf(ccAt(i * NS + j) - corr) / denomS[i * NS + j];
                if (v != v) v = 0.f;
                return v;
            };
            float lc  = logf(nccAt(shx, shy));
            float lxm = logf(nccAt(shx - 1, shy));
            float lxp = logf(nccAt(shx + 1, shy));
            float lym = logf(nccAt(shx, shy - 1));
            float lyp = logf(nccAt(shx, shy + 1));
            float shxn = -(float)(shx - 10) - (lxm - lxp) / (2.f * lxm - 4.f * lc + 2.f * lxp);
            float shyn = -(float)(shy - 10) - (lym - lyp) / (2.f * lym - 4.f * lc + 2.f * lyp);
            shifts[b]      = shxn;   // dy
            shifts[32 + b] = shyn;   // dx
        }
    }
}

// ---------------- Kernel B: bilinear warp + transposed write ----------------
__device__ __forceinline__ float samp(const float* __restrict__ img, int y, int x) {
    bool valid = (y >= 0) & (y < HH) & (x >= 0) & (x < WW);
    int yc = min(max(y, 0), HH - 1), xc = min(max(x, 0), WW - 1);
    float v = img[(size_t)yc * WW + xc];
    return valid ? v : 0.f;
}

__global__ __launch_bounds__(256) void warp_kernel(
    const float* __restrict__ fr, const float* __restrict__ shifts,
    float* __restrict__ out)
{
    int b  = blockIdx.z;
    int h0 = blockIdx.y * 32;
    int w0 = blockIdx.x * 32;
    float dy = shifts[b], dx = shifts[32 + b];
    const float* img = fr + (size_t)b * NPIX;
    __shared__ float tile[32][33];
    int tx = threadIdx.x & 31;
    int tz = threadIdx.x >> 5;
#pragma unroll
    for (int s = 0; s < 4; ++s) {
        int h = h0 + tz + 8 * s;
        int w = w0 + tx;
        float yq = (float)h - dy;
        float xq = (float)w - dx;
        float y0f = floorf(yq), x0f = floorf(xq);
        float wy = yq - y0f, wx = xq - x0f;
        int y0 = (int)y0f, x0 = (int)x0f;
        float v00 = samp(img, y0,     x0);
        float v01 = samp(img, y0,     x0 + 1);
        float v10 = samp(img, y0 + 1, x0);
        float v11 = samp(img, y0 + 1, x0 + 1);
        float val = v00 * (1.f - wy) * (1.f - wx) + v01 * (1.f - wy) * wx
                  + v10 * wy * (1.f - wx)         + v11 * wy * wx;
        tile[tz + 8 * s][tx] = val;
    }
    __syncthreads();
#pragma unroll
    for (int s = 0; s < 4; ++s) {
        int hh = tx;
        int ww = tz + 8 * s;
        out[(size_t)b * NPIX + (size_t)(w0 + ww) * HH + (h0 + hh)] = tile[hh][ww];
    }
}

// ---------------- launch ----------------------------------------------------
extern "C" void kernel_launch(void* const* d_in, const int* in_sizes, int n_in,
                              void* d_out, int out_size, void* d_ws, size_t ws_size,
                              hipStream_t stream) {
    const float* fr  = (const float*)d_in[0];   // (1,32,512,512,1) flat
    const float* tpl = (const float*)d_in[1];   // (512,512)
    float* out = (float*)d_out;
    char* ws = (char*)d_ws;

    // ws layout (~23 MB), every buffer fully rewritten each launch -> no memset
    unsigned short* tplb = (unsigned short*)(ws + 0);        // 1.11 MB (2 copies)
    float*  I1p    = (float*) (ws + 2097152);                // 512 KB (256*512 f)
    float*  I2p    = (float*) (ws + 2621440);                // 512 KB
    double* tplS1p = (double*)(ws + 3145728);                // 512 B
    double* tplS2p = (double*)(ws + 3146240);                // 512 B
    float*  shifts = (float*) (ws + 3146752);                // 256 B
    float*  cc8    = (float*) (ws + 4194304);                // 458 KB
    float*  part   = (float*) (ws + 8388608);                // 14.68 MB (256 chunks)

    prep_tpl  <<<128, 512, 0, stream>>>(tpl, tplb);
    corr_mfma <<<576, 896, 0, stream>>>(fr, tplb, tpl, part, I1p, I2p, tplS1p, tplS2p);
    reduce_k  <<<224, 512, 0, stream>>>(part, cc8);
    stage2_am <<<32, 512, 0, stream>>>(cc8, fr, I1p, I2p, tplS1p, tplS2p, shifts);
    warp_kernel<<<dim3(16, 16, 32), 256, 0, stream>>>(fr, shifts, out);
}

// Round 17
// 136.143 us; speedup vs baseline: 1.2620x; 1.0820x over previous
//
#include <hip/hip_runtime.h>
#include <math.h>

#define HH 512
#define WW 512
#define NPIX (HH*WW)
#define NB 32
#define NS 21           // 2*MS+1 shifts per axis
#define KWIN 492        // window size (H - 2*10)
#define NKB 256         // split-K chunks (1024 k each)
#define MT28 28         // m-tiles (448 = 28*16, M=441 padded)
#define PARTSZ (MT28*32*16)   // 14336 floats per k-chunk
#define TPLB_COPY 278528      // 512*544 shorts per parity copy

typedef __attribute__((ext_vector_type(8))) short short8;
typedef __attribute__((ext_vector_type(4))) float floatx4;

__device__ __forceinline__ unsigned short f2bf(float f) {
    unsigned u = __float_as_uint(f);
    unsigned r = (u + 0x7fffu + ((u >> 16) & 1u)) >> 16;
    return (unsigned short)r;
}

// 16B fragment load from a 4B-aligned address (tplb cols are even, not x8).
__device__ __forceinline__ short8 loadA(const unsigned short* p) {
    union { short8 v; unsigned u[4]; } r;
    const unsigned* q = (const unsigned*)p;
    r.u[0] = q[0]; r.u[1] = q[1]; r.u[2] = q[2]; r.u[3] = q[3];
    return r.v;
}

// ---------------- prep_tpl: padded bf16 template only (128 blocks) ----------
__global__ __launch_bounds__(512) void prep_tpl(
    const float* __restrict__ tpl, unsigned short* __restrict__ tplb)
{
    int t   = threadIdx.x;
    int sy0 = blockIdx.x * 4;                         // 128 blocks x 4 rows
#pragma unroll
    for (int rr = 0; rr < 4; ++rr) {
        int sy = sy0 + rr;
        const float* srow = tpl + (size_t)sy * WW;
#pragma unroll
        for (int P = 0; P < 2; ++P) {
            for (int c = t; c < 544; c += 512) {
                int sx = (c + 496 - P) & 511;         // (c-16-P) mod 512
                tplb[(size_t)P * TPLB_COPY + (size_t)sy * 544 + c] = f2bf(srow[sx]);
            }
        }
    }
}

// ---------------- Kernel C: corr MFMA + fused prep sums ---------------------
// blocks [0,256):   R10 corr: NKB=256 chunks of 1024 k, 896 thr = 14 waves x
//                   2 m-tiles, two 512-k sub-chunks staged into LDS seq.,
//                   accumulating in registers. part = 14.7 MB.
// blocks [256,512): interior column partial sums (frame b, row-oct), t<512.
// blocks [512,576): template partial sums (64 jobs of 8 rows), t<512.
// blocks [576,736): EDGE-ROW sums: 1280 rows (32 frames x 40 edge rows), one
//                   row per wave, WAVES 0..7 ONLY (R16 crash: 14 waves made
//                   the last block read frame 32 = OOB). Feeds stage2's
//                   prefix-based window totals (kills its 21 serial reduces).
__global__ __launch_bounds__(896) void corr_mfma(
    const float* __restrict__ fr, const unsigned short* __restrict__ tplb,
    const float* __restrict__ tpl, float* __restrict__ part,
    float* __restrict__ I1p, float* __restrict__ I2p,
    double* __restrict__ tplS1p, double* __restrict__ tplS2p,
    double* __restrict__ rowS1, double* __restrict__ rowS2)
{
    __shared__ unsigned short Bs[16384];   // 32 KB (corr branch)
    __shared__ double jb1[8], jb2[8];      // template-sum branch

    const int blk = blockIdx.x;
    const int t   = threadIdx.x;

    if (blk >= 576) {                      // edge-row sums, one row per wave
        int wvv = t >> 6;
        if (wvv < 8) {                     // waves 0..7 only: rid in [0,1280)
            int rid  = (blk - 576) * 8 + wvv;
            int lane = t & 63;
            int b = rid / 40, j2 = rid % 40;
            int y = (j2 < 20) ? j2 : (472 + j2);  // top rows 0..19, bot 492..511
            const float* row = fr + (size_t)b * NPIX + (size_t)y * WW;
            double d1 = 0.0, d2 = 0.0;
#pragma unroll
            for (int i = 0; i < 8; ++i) {
                float v = row[lane + 64 * i];
                d1 += (double)v;
                d2 += (double)(v * v);
            }
            for (int off = 32; off; off >>= 1) {
                d1 += __shfl_down(d1, off);
                d2 += __shfl_down(d2, off);
            }
            if (lane == 0) { rowS1[rid] = d1; rowS2[rid] = d2; }
        }
        return;
    }
    if (blk >= 512) {                      // template partial sums
        int tj = blk - 512;
        if (t < 512) {
            const float* trow = tpl + (size_t)tj * 8 * WW;
            float s1 = 0.f, s2 = 0.f;
            for (int y = 0; y < 8; ++y) {
                float v = trow[(size_t)y * WW + t];
                s1 += v; s2 += v * v;
            }
            double d1 = (double)s1, d2 = (double)s2;
            for (int off = 32; off; off >>= 1) {
                d1 += __shfl_down(d1, off);
                d2 += __shfl_down(d2, off);
            }
            int lane = t & 63, wv = t >> 6;
            if (lane == 0) { jb1[wv] = d1; jb2[wv] = d2; }
        }
        __syncthreads();
        if (t == 0) {
            double a = 0.0, c = 0.0;
            for (int i = 0; i < 8; ++i) { a += jb1[i]; c += jb2[i]; }
            tplS1p[tj] = a; tplS2p[tj] = c;
        }
        return;
    }
    if (blk >= 256) {                      // interior column partial sums
        if (t < 512) {
            int id = blk - 256;
            int b = id >> 3, oct = id & 7;
            const float* img = fr + (size_t)b * NPIX;
            float s1 = 0.f, s2 = 0.f;
            int y0 = 20 + 59 * oct;                   // rows 20..491 = 8*59
            for (int y = y0; y < y0 + 59; ++y) {
                float v = img[(size_t)y * WW + t];
                s1 += v; s2 += v * v;
            }
            I1p[(size_t)id * 512 + t] = s1;
            I2p[(size_t)id * 512 + t] = s2;
        }
        return;
    }

    // ---------------- corr branch (identical to R10/R15) --------------------
    const int l   = t & 63;
    const int wid = t >> 6;               // wave 0..13 = tile-pair
    const int idx = blk;                  // 0..255
    const int kb  = ((idx & 7) << 5) | (idx >> 3);   // XCD swizzle (32/XCD)
    const int kg  = l >> 4;               // k-group 0..3
    const int ln  = l & 15;

    int du0, dv0, du1, dv1;
    {
        int m_g = 32 * wid + ln;           // mt = 0
        du0 = (m_g * 1561) >> 15;          // m_g/21 exact for m_g<=447
        dv0 = m_g - 21 * du0;
        if (m_g >= 441) { du0 = 0; dv0 = 0; }   // pad rows: loaded, never used
        m_g = 32 * wid + 16 + ln;          // mt = 1
        du1 = (m_g * 1561) >> 15;
        dv1 = m_g - 21 * du1;
        if (m_g >= 441) { du1 = 0; dv1 = 0; }
    }
    const int P0 = dv0 & 1, P1 = dv1 & 1;
    const int col0 = 8 * kg - dv0 + 26 + P0;
    const int col1 = 8 * kg - dv1 + 26 + P1;

    const unsigned short* lB = Bs + kg * 256 + ln * 8;

    floatx4 acc00 = {}, acc01 = {}, acc10 = {}, acc11 = {};

#pragma unroll 1
    for (int c = 0; c < 2; ++c) {
        const int row = 2 * kb + c;          // template/frame image row
        const int k0  = row << 9;            // global k base of this sub-chunk
        if (c) __syncthreads();              // WAR on Bs
        for (int i = t; i < 4096; i += 896) {
            int frame = i >> 7, q = i & 127;
            float4 v = *(const float4*)(fr + (size_t)frame * NPIX + k0 + 4 * q);
            int k8 = q >> 1, j4 = (q & 1) * 4;
            ushort4 o;
            o.x = f2bf(v.x); o.y = f2bf(v.y); o.z = f2bf(v.z); o.w = f2bf(v.w);
            *(ushort4*)&Bs[(k8 * 32 + frame) * 8 + j4] = o;
        }
        __syncthreads();

        const unsigned short* pA0 = tplb + (size_t)P0 * TPLB_COPY
            + (size_t)((row + 522 - du0) & 511) * 544 + col0;
        const unsigned short* pA1 = tplb + (size_t)P1 * TPLB_COPY
            + (size_t)((row + 522 - du1) & 511) * 544 + col1;

#pragma unroll
        for (int ks = 0; ks < 16; ++ks) {    // 16 steps x 32 k = 512
            short8 A0 = loadA(pA0);
            short8 A1 = loadA(pA1);
            short8 B0 = *(const short8*)(lB + ks * 1024);         // frames 0..15
            short8 B1 = *(const short8*)(lB + ks * 1024 + 128);   // frames 16..31
            acc00 = __builtin_amdgcn_mfma_f32_16x16x32_bf16(A0, B0, acc00, 0, 0, 0);
            acc01 = __builtin_amdgcn_mfma_f32_16x16x32_bf16(A0, B1, acc01, 0, 0, 0);
            acc10 = __builtin_amdgcn_mfma_f32_16x16x32_bf16(A1, B0, acc10, 0, 0, 0);
            acc11 = __builtin_amdgcn_mfma_f32_16x16x32_bf16(A1, B1, acc11, 0, 0, 0);
            pA0 += 32; pA1 += 32;
        }
    }

    // dense partial stores: part[((kb*28 + mtile)*32 + n)*16 + mr], mr=4kg+r
    {
        size_t base = ((size_t)kb * MT28 + 2 * wid) * 32;
        floatx4* p;
        p = (floatx4*)(part + (base + ln)      * 16 + 4 * kg); *p = acc00;
        p = (floatx4*)(part + (base + 16 + ln) * 16 + 4 * kg); *p = acc01;
        p = (floatx4*)(part + (base + 32 + ln) * 16 + 4 * kg); *p = acc10;
        p = (floatx4*)(part + (base + 48 + ln) * 16 + 4 * kg); *p = acc11;
    }
}

// ---------------- reduce: part (256 k-chunks) -> cc8 (8 oct partials) -------
__global__ __launch_bounds__(512) void reduce_k(
    const float* __restrict__ part, float* __restrict__ cc8)
{
    int blk = blockIdx.x;
    int oct = blk / 28;                      // 0..7 (32 kb-chunks each)
    int j   = (blk % 28) * 512 + threadIdx.x;
    const float* p = part + (size_t)(oct * 32) * PARTSZ + j;
    float s = 0.f;
#pragma unroll 8
    for (int i = 0; i < 32; ++i)
        s += p[(size_t)i * PARTSZ];
    cc8[(size_t)oct * PARTSZ + j] = s;
}

// ---------------- stage2 + argmax: 32 blocks (one per frame) ----------------
// REWRITTEN: the 21 serial double wave-reduces (R15 profile: ~48 us, 2%
// occupancy latency chain) are replaced by ONE wave-reduce (u=0 totals) +
// scalar prefix over precomputed edge-row sums:
//   totals[u] = T0 + sum_{j<u}(S_bot_j - S_top_j);  sum1b = T0 + sum_j S_bot_j.
__global__ __launch_bounds__(512) void stage2_am(
    const float* __restrict__ cc8, const float* __restrict__ fr,
    const float* __restrict__ I1p, const float* __restrict__ I2p,
    const double* __restrict__ tplS1p, const double* __restrict__ tplS2p,
    const double* __restrict__ rowS1, const double* __restrict__ rowS2,
    float* __restrict__ shifts)
{
    __shared__ float  e1[NS][40], e2[NS][40];
    __shared__ double totals1[NS], totals2[NS];
    __shared__ float  denomS[NS * NS];
    __shared__ double tS1s, tS2s, sum1b;
    __shared__ double w1[8], w2[8];
    __shared__ double rs1[40], rs2[40];

    int b = blockIdx.x;
    int x = threadIdx.x;
    const float* img = fr + (size_t)b * NPIX;

    float top[20];
#pragma unroll
    for (int y = 0; y < 20; ++y) top[y] = img[(size_t)y * WW + x];
    float t1 = 0.f, t2 = 0.f;
#pragma unroll
    for (int y = 0; y < 20; ++y) { t1 += top[y]; t2 += top[y] * top[y]; }

    float i1 = 0.f, i2 = 0.f;
#pragma unroll
    for (int o = 0; o < 8; ++o) {
        i1 += I1p[((size_t)(b * 8 + o)) * 512 + x];
        i2 += I2p[((size_t)(b * 8 + o)) * 512 + x];
    }
    int lane = x & 63, wv = x >> 6;

    // stage edge-row sums into LDS
    if (x < 40) { rs1[x] = rowS1[b * 40 + x]; rs2[x] = rowS2[b * 40 + x]; }

    // template totals (64 partials -> wave 0)
    if (x < 64) {
        double d1 = tplS1p[x], d2 = tplS2p[x];
        for (int off = 32; off; off >>= 1) {
            d1 += __shfl_down(d1, off);
            d2 += __shfl_down(d2, off);
        }
        if (x == 0) { tS1s = d1; tS2s = d2; }
    }

    // ONE wave-reduce: u=0 window totals T0 = sum_x (i1+t1), (i2+t2)
    {
        double d1 = (double)(i1 + t1), d2 = (double)(i2 + t2);
        for (int off = 32; off; off >>= 1) {
            d1 += __shfl_down(d1, off);
            d2 += __shfl_down(d2, off);
        }
        if (lane == 0) { w1[wv] = d1; w2[wv] = d2; }
    }

    // edge-column register slides (only the 40 edge threads)
    if (x < 20 || x >= 492) {
        float bot[20];
#pragma unroll
        for (int y = 0; y < 20; ++y) bot[y] = img[(size_t)(492 + y) * WW + x];
        int xi = (x < 20) ? x : (x - 472);
        float s1 = i1 + t1, s2 = i2 + t2;
#pragma unroll
        for (int u = 0; u < NS; ++u) {
            if (u) {
                float a = top[u-1], c = bot[u-1];
                s1 += c - a;
                s2 += c * c - a * a;
            }
            e1[u][xi] = s1; e2[u][xi] = s2;
        }
    }
    __syncthreads();

    if (x == 0) {
        double a = 0.0, c = 0.0;
        for (int i = 0; i < 8; ++i) { a += w1[i]; c += w2[i]; }
        double p1 = a, p2 = c;
        totals1[0] = p1; totals2[0] = p2;
        for (int u = 1; u < NS; ++u) {
            p1 += rs1[20 + u - 1] - rs1[u - 1];
            p2 += rs2[20 + u - 1] - rs2[u - 1];
            totals1[u] = p1; totals2[u] = p2;
        }
        double sb = 0.0;
        for (int j = 0; j < 20; ++j) sb += rs1[20 + j];
        sum1b = a + sb;                     // frame total
    }
    __syncthreads();

    if (x < NS * NS) {
        int u = x / NS, v = x - NS * u;
        double S1 = totals1[u], S2 = totals2[u];
        for (int j = 0; j < v; ++j)  { S1 -= (double)e1[u][j];      S2 -= (double)e2[u][j]; }
        for (int j = v; j < 20; ++j) { S1 -= (double)e1[u][20 + j]; S2 -= (double)e2[u][20 + j]; }
        const double inv = 1.0 / ((double)KWIN * (double)KWIN);
        double m1 = S1 * inv, m2 = S2 * inv;
        double var = m2 - (m1 * m1) * inv + 1e-8;   // reference's formula
        if (var < 0.0) var = 0.0;
        double tv = tS2s - tS1s * tS1s * (1.0 / (double)NPIX) + 1e-8;
        denomS[x] = (float)sqrt(tv * var);
    }
    __syncthreads();

    if (x < 64) {
        float corr = (float)(sum1b * tS1s * (1.0 / (double)NPIX));
        auto ccAt = [&](int m) -> float {
            int jj = ((m >> 4) * 512) + b * 16 + (m & 15);
            float s = 0.f;
#pragma unroll
            for (int o = 0; o < 8; ++o) s += cc8[(size_t)o * PARTSZ + jj];
            return s;
        };
        float best = -1e30f; int bidx = NS * NS;
        for (int i = x; i < NS * NS; i += 64) {
            float v = fabsf(ccAt(i) - corr) / denomS[i];
            if (v != v) v = 0.f;               // NaN -> 0 (matches reference)
            if (v > best) { best = v; bidx = i; }
        }
        for (int off = 32; off; off >>= 1) {
            float ov = __shfl_down(best, off);
            int   oi = __shfl_down(bidx, off);
            if (ov > best || (ov == best && oi < bidx)) { best = ov; bidx = oi; }
        }
        if (x == 0) {
            int shx = bidx / NS, shy = bidx % NS;
            auto nccAt = [&](int i, int j) -> float {
                i = (i < 0) ? i + NS : i; i = (i > NS - 1) ? NS - 1 : i;  // jnp wrap-then-clamp
                j = (j < 0) ? j + NS : j; j = (j > NS - 1) ? NS - 1 : j;
                float v = fabsf(ccAt(i * NS + j) - corr) / denomS[i * NS + j];
                if (v != v) v = 0.f;
                return v;
            };
            float lc  = logf(nccAt(shx, shy));
            float lxm = logf(nccAt(shx - 1, shy));
            float lxp = logf(nccAt(shx + 1, shy));
            float lym = logf(nccAt(shx, shy - 1));
            float lyp = logf(nccAt(shx, shy + 1));
            float shxn = -(float)(shx - 10) - (lxm - lxp) / (2.f * lxm - 4.f * lc + 2.f * lxp);
            float shyn = -(float)(shy - 10) - (lym - lyp) / (2.f * lym - 4.f * lc + 2.f * lyp);
            shifts[b]      = shxn;   // dy
            shifts[32 + b] = shyn;   // dx
        }
    }
}

// ---------------- Kernel B: bilinear warp + transposed write ----------------
__device__ __forceinline__ float samp(const float* __restrict__ img, int y, int x) {
    bool valid = (y >= 0) & (y < HH) & (x >= 0) & (x < WW);
    int yc = min(max(y, 0), HH - 1), xc = min(max(x, 0), WW - 1);
    float v = img[(size_t)yc * WW + xc];
    return valid ? v : 0.f;
}

__global__ __launch_bounds__(256) void warp_kernel(
    const float* __restrict__ fr, const float* __restrict__ shifts,
    float* __restrict__ out)
{
    int b  = blockIdx.z;
    int h0 = blockIdx.y * 32;
    int w0 = blockIdx.x * 32;
    float dy = shifts[b], dx = shifts[32 + b];
    const float* img = fr + (size_t)b * NPIX;
    __shared__ float tile[32][33];
    int tx = threadIdx.x & 31;
    int tz = threadIdx.x >> 5;
#pragma unroll
    for (int s = 0; s < 4; ++s) {
        int h = h0 + tz + 8 * s;
        int w = w0 + tx;
        float yq = (float)h - dy;
        float xq = (float)w - dx;
        float y0f = floorf(yq), x0f = floorf(xq);
        float wy = yq - y0f, wx = xq - x0f;
        int y0 = (int)y0f, x0 = (int)x0f;
        float v00 = samp(img, y0,     x0);
        float v01 = samp(img, y0,     x0 + 1);
        float v10 = samp(img, y0 + 1, x0);
        float v11 = samp(img, y0 + 1, x0 + 1);
        float val = v00 * (1.f - wy) * (1.f - wx) + v01 * (1.f - wy) * wx
                  + v10 * wy * (1.f - wx)         + v11 * wy * wx;
        tile[tz + 8 * s][tx] = val;
    }
    __syncthreads();
#pragma unroll
    for (int s = 0; s < 4; ++s) {
        int hh = tx;
        int ww = tz + 8 * s;
        out[(size_t)b * NPIX + (size_t)(w0 + ww) * HH + (h0 + hh)] = tile[hh][ww];
    }
}

// ---------------- launch ----------------------------------------------------
extern "C" void kernel_launch(void* const* d_in, const int* in_sizes, int n_in,
                              void* d_out, int out_size, void* d_ws, size_t ws_size,
                              hipStream_t stream) {
    const float* fr  = (const float*)d_in[0];   // (1,32,512,512,1) flat
    const float* tpl = (const float*)d_in[1];   // (512,512)
    float* out = (float*)d_out;
    char* ws = (char*)d_ws;

    // ws layout (~23 MB), every buffer fully rewritten each launch -> no memset
    unsigned short* tplb = (unsigned short*)(ws + 0);        // 1.11 MB (2 copies)
    float*  I1p    = (float*) (ws + 2097152);                // 512 KB (256*512 f)
    float*  I2p    = (float*) (ws + 2621440);                // 512 KB
    double* tplS1p = (double*)(ws + 3145728);                // 512 B
    double* tplS2p = (double*)(ws + 3146240);                // 512 B
    float*  shifts = (float*) (ws + 3146752);                // 256 B
    double* rowS1  = (double*)(ws + 3276800);                // 10.24 KB (1280 d)
    double* rowS2  = (double*)(ws + 3287040);                // 10.24 KB
    float*  cc8    = (float*) (ws + 4194304);                // 458 KB
    float*  part   = (float*) (ws + 8388608);                // 14.68 MB (256 chunks)

    prep_tpl  <<<128, 512, 0, stream>>>(tpl, tplb);
    corr_mfma <<<736, 896, 0, stream>>>(fr, tplb, tpl, part, I1p, I2p,
                                        tplS1p, tplS2p, rowS1, rowS2);
    reduce_k  <<<224, 512, 0, stream>>>(part, cc8);
    stage2_am <<<32, 512, 0, stream>>>(cc8, fr, I1p, I2p, tplS1p, tplS2p,
                                       rowS1, rowS2, shifts);
    warp_kernel<<<dim3(16, 16, 32), 256, 0, stream>>>(fr, shifts, out);
}